// Round 1
// baseline (145.439 us; speedup 1.0000x reference)
//
#include <hip/hip_runtime.h>
#include <math.h>

#define T_STEPS 64
#define D_OUT 256

// One block per (n,c); one thread per output channel j.
// x:(T,NC,2) staged to LDS; delay/stochastic-rounding path in fp64 to match
// the float64 numpy reference bit-for-bit on the noise<frac threshold.
__global__ __launch_bounds__(256) void jeffress_kernel(
    const float* __restrict__ x,          // (T, NC, 2)
    const float* __restrict__ log_delay,  // (D_OUT)
    const float* __restrict__ log_weight, // (1)
    const float* __restrict__ noise,      // (NC, D_OUT, 2)
    float* __restrict__ out,              // (T, NC, D_OUT)
    int NC)
{
    __shared__ float xs0[T_STEPS];
    __shared__ float xs1[T_STEPS];
    __shared__ int maxd[2];

    const int nc = blockIdx.x;
    const int j  = threadIdx.x;

    // Stage x[:, nc, :] into LDS (threads 0..63, one float2 each)
    if (j < T_STEPS) {
        const float* xp = x + ((size_t)j * NC + nc) * 2;
        xs0[j] = xp[0];
        xs1[j] = xp[1];
    }
    __syncthreads();

    // argmax over time (first occurrence of max -> strict '>')
    if (j < 2) {
        const float* xsrc = (j == 0) ? xs0 : xs1;
        float best = xsrc[0];
        int bi = 0;
        for (int t = 1; t < T_STEPS; ++t) {
            float v = xsrc[t];
            if (v > best) { best = v; bi = t; }
        }
        maxd[j] = (T_STEPS - 1) - bi;
    }
    __syncthreads();

    // Delay + stochastic rounding in double precision.
    // delay[j][0] = exp(log_delay[j]); delay[j][1] = exp(log_delay[D-1-j])
    double ld0 = (double)log_delay[j];
    double ld1 = (double)log_delay[(D_OUT - 1) - j];
    double s0 = (double)T_STEPS * exp(ld0);
    double s1 = (double)T_STEPS * exp(ld1);
    double f0 = floor(s0), f1 = floor(s1);

    const float* nptr = noise + ((size_t)nc * D_OUT + j) * 2;
    float n0 = nptr[0], n1 = nptr[1];

    int r0 = (int)f0 + (((double)n0 < (s0 - f0)) ? 1 : 0);
    int r1 = (int)f1 + (((double)n1 < (s1 - f1)) ? 1 : 0);
    int rd0 = min(r0, maxd[0]);   // 0 <= rd < T
    int rd1 = min(r1, maxd[1]);

    const float w = (float)exp((double)log_weight[0]);

    // Leaky integrator over circularly-shifted x, decay = 1 - 1/2 = 0.5 exact
    float y0 = 0.f, y1 = 0.f;
    float* op = out + (size_t)nc * D_OUT + j;
    const size_t ostride = (size_t)NC * D_OUT;
    #pragma unroll
    for (int t = 0; t < T_STEPS; ++t) {
        y0 = y0 * 0.5f + xs0[(t - rd0) & (T_STEPS - 1)];
        y1 = y1 * 0.5f + xs1[(t - rd1) & (T_STEPS - 1)];
        op[(size_t)t * ostride] = (y0 + y1) * w;
    }
}

extern "C" void kernel_launch(void* const* d_in, const int* in_sizes, int n_in,
                              void* d_out, int out_size, void* d_ws, size_t ws_size,
                              hipStream_t stream) {
    const float* x          = (const float*)d_in[0];
    const float* log_delay  = (const float*)d_in[1];
    const float* log_weight = (const float*)d_in[2];
    const float* noise      = (const float*)d_in[3];
    float* out = (float*)d_out;

    const int NC = in_sizes[3] / (D_OUT * 2);  // noise = (N,C,D_OUT,2)

    jeffress_kernel<<<NC, D_OUT, 0, stream>>>(x, log_delay, log_weight, noise, out, NC);
}